// Round 11
// baseline (246.223 us; speedup 1.0000x reference)
//
#include <hip/hip_runtime.h>
#include <hip/hip_bf16.h>
#include <math.h>

#define Bsz 2
#define Cch 48
#define Hh 64
#define Ww 64
#define Nn 4096

typedef __bf16 bf16;
typedef __attribute__((ext_vector_type(8))) __bf16 bf16x8;
typedef __attribute__((ext_vector_type(4))) float f32x4;

// ---------------- K1: conv1x1, thread-per-pixel, all 48 outputs --------------
// Reads x ONCE (48 coalesced loads/thread) vs 48x re-read before. Emits:
// qnc (B,N,48) fp32, q_bf (B,N,64) bf16 (zero-padded), xnc (B,N,48) fp32 —
// all row-major, written coalesced via per-wave LDS staging (same-wave RAW).
__global__ __launch_bounds__(128) void k_conv1x1(const float* __restrict__ x,
                          const float* __restrict__ Wt,
                          const float* __restrict__ bias, float* __restrict__ qnc,
                          bf16* __restrict__ qbf, float* __restrict__ xnc){
  __shared__ float wqT[2304];          // wqT[c*48+o] = Wt[o*48+c]
  __shared__ float stage[2][64][49];   // per-wave row staging (pad 49)
  int tid = threadIdx.x;
  for (int f = tid; f < 2304; f += 128){
    int o = f / 48, c = f - o * 48;
    wqT[c * 48 + o] = Wt[f];
  }
  __syncthreads();
  int idx = blockIdx.x * 128 + tid;    // global row = b*Nn+p
  int b = idx >> 12, p = idx & (Nn - 1);
  int wv = tid >> 6, lane = tid & 63;
  int row0 = blockIdx.x * 128 + wv * 64;   // wave's first row
  // read x row (coalesced per c across lanes)
  float xrow[48];
  #pragma unroll
  for (int c = 0; c < 48; c++) xrow[c] = x[((size_t)(b * 48 + c)) * Nn + p];
  // stage + coop-store xnc (contiguous float4, same-wave)
  #pragma unroll
  for (int c = 0; c < 48; c++) stage[wv][lane][c] = xrow[c];
  {
    float* dst = xnc + (size_t)row0 * 48;
    #pragma unroll
    for (int f = 0; f < 12; f++){
      int g = lane + f * 64;             // 768 float4s
      int px = g / 12, c4 = (g % 12) * 4;
      *(float4*)&dst[px * 48 + c4] = *(const float4*)&stage[wv][px][c4];
    }
  }
  // compute all 48 outputs
  float acc[48];
  #pragma unroll
  for (int o = 0; o < 48; o++) acc[o] = bias[o];
  #pragma unroll
  for (int c = 0; c < 48; c++){
    float xv = xrow[c];
    const float4* wr = (const float4*)&wqT[c * 48];
    #pragma unroll
    for (int j = 0; j < 12; j++){
      float4 w = wr[j];                  // LDS broadcast (conflict-free)
      acc[j * 4 + 0] = fmaf(xv, w.x, acc[j * 4 + 0]);
      acc[j * 4 + 1] = fmaf(xv, w.y, acc[j * 4 + 1]);
      acc[j * 4 + 2] = fmaf(xv, w.z, acc[j * 4 + 2]);
      acc[j * 4 + 3] = fmaf(xv, w.w, acc[j * 4 + 3]);
    }
  }
  // stage + coop-store qnc and q_bf
  #pragma unroll
  for (int c = 0; c < 48; c++) stage[wv][lane][c] = acc[c];
  {
    float* dst = qnc + (size_t)row0 * 48;
    #pragma unroll
    for (int f = 0; f < 12; f++){
      int g = lane + f * 64;
      int px = g / 12, c4 = (g % 12) * 4;
      *(float4*)&dst[px * 48 + c4] = *(const float4*)&stage[wv][px][c4];
    }
    bf16* qb = qbf + (size_t)row0 * 64;
    #pragma unroll
    for (int f = 0; f < 64; f++){
      int g = lane + f * 64;             // 4096 bf16, ch inner -> coalesced
      int px = g >> 6, ch = g & 63;
      qb[g] = (ch < 48) ? (bf16)stage[wv][px][ch] : (bf16)0.f;
    }
  }
}

// ---------------- K2: wave-per-pixel dw3x3 + LN + GELU + pw + tanh -> pos ----
__global__ __launch_bounds__(256) void k_offset_pos(const float* __restrict__ qnc,
                             const float* __restrict__ dww,
                             const float* __restrict__ dwb, const float* __restrict__ lng,
                             const float* __restrict__ lnb, const float* __restrict__ pww,
                             float* __restrict__ pos){
  int wv = threadIdx.x >> 6, lane = threadIdx.x & 63;
  int idx = blockIdx.x * 4 + wv;          // (b,pixel)
  int b = idx >> 12;
  int p = idx & (Nn - 1);
  int y = p >> 6, x = p & 63;
  int c = lane;
  float t = 0.f;
  if (c < 48){
    t = dwb[c];
    #pragma unroll
    for (int ky = -1; ky <= 1; ky++){
      int yy = y + ky;
      if (yy < 0 || yy >= Hh) continue;          // wave-uniform branch
      #pragma unroll
      for (int kx = -1; kx <= 1; kx++){
        int xx = x + kx;
        if (xx < 0 || xx >= Ww) continue;        // wave-uniform branch
        t = fmaf(qnc[((size_t)(b * Nn + yy * Ww + xx)) * 48 + c],
                 dww[c * 9 + (ky + 1) * 3 + (kx + 1)], t);
      }
    }
  }
  float s = t;
  #pragma unroll
  for (int m = 1; m < 64; m <<= 1) s += __shfl_xor(s, m);
  float mean = s * (1.f / 48.f);
  float d = (c < 48) ? (t - mean) : 0.f;
  float v = d * d;
  #pragma unroll
  for (int m = 1; m < 64; m <<= 1) v += __shfl_xor(v, m);
  float rstd = rsqrtf(v * (1.f / 48.f) + 1e-5f);
  float p0 = 0.f, p1 = 0.f;
  if (c < 48){
    float u = (t - mean) * rstd * lng[c] + lnb[c];
    u = 0.5f * u * (1.f + erff(u * 0.70710678118654752f));   // exact gelu
    p0 = pww[c] * u;
    p1 = pww[48 + c] * u;
  }
  #pragma unroll
  for (int m = 1; m < 64; m <<= 1){ p0 += __shfl_xor(p0, m); p1 += __shfl_xor(p1, m); }
  if (lane == 0){
    float posy = tanhf(p0) * (2.f / 63.f) + ((0.5f + (float)y) * (2.f / 63.f) - 1.f);
    float posx = tanhf(p1) * (2.f / 63.f) + ((0.5f + (float)x) * (2.f / 63.f) - 1.f);
    pos[idx * 2 + 0] = posy;
    pos[idx * 2 + 1] = posx;
  }
}

// ---------------- K3: wave-per-key fused sample + k,v projection -------------
// taps now read xnc rows (48 consecutive floats) instead of 48-CL scatters.
__global__ __launch_bounds__(512) void k_samplekv(const float* __restrict__ xnc,
                           const float* __restrict__ pos,
                           const float* __restrict__ Wk, const float* __restrict__ bk,
                           const float* __restrict__ Wv, const float* __restrict__ bv,
                           bf16* __restrict__ kk_bf, bf16* __restrict__ vt_bf,
                           float2* __restrict__ axay){
  __shared__ float wkt[48][49];   // wkt[c][o] = Wk[o][c]
  __shared__ float wvt[48][49];
  __shared__ float rowb[8][48];
  int tid = threadIdx.x;
  for (int f = tid; f < 2304; f += 512){
    int o = f / 48, c = f - o * 48;
    wkt[c][o] = Wk[f];
    wvt[c][o] = Wv[f];
  }
  __syncthreads();
  int wv = tid >> 6, lane = tid & 63;
  int idx = blockIdx.x * 8 + wv;
  int b = idx >> 12;
  int n = idx & (Nn - 1);
  float py = pos[idx * 2], px = pos[idx * 2 + 1];
  if (lane == 0) axay[idx] = make_float2(95.f - 47.5f * py, 95.f - 47.5f * px);
  float gx = (px + 1.f) * 0.5f * 63.f;
  float gy = (py + 1.f) * 0.5f * 63.f;
  float x0f = floorf(gx), y0f = floorf(gy);
  float wx = gx - x0f, wy = gy - y0f;
  int x0 = (int)x0f, y0 = (int)y0f, x1 = x0 + 1, y1 = y0 + 1;
  float w00 = (1.f - wy) * (1.f - wx), w01 = (1.f - wy) * wx;
  float w10 = wy * (1.f - wx),         w11 = wy * wx;
  bool vx0 = (x0 >= 0) && (x0 < Ww), vx1 = (x1 >= 0) && (x1 < Ww);
  bool vy0 = (y0 >= 0) && (y0 < Hh), vy1 = (y1 >= 0) && (y1 < Hh);
  if (!(vx0 && vy0)) w00 = 0.f;
  if (!(vx1 && vy0)) w01 = 0.f;
  if (!(vx0 && vy1)) w10 = 0.f;
  if (!(vx1 && vy1)) w11 = 0.f;
  int cx0 = min(max(x0, 0), Ww - 1), cx1 = min(max(x1, 0), Ww - 1);
  int cy0 = min(max(y0, 0), Hh - 1), cy1 = min(max(y1, 0), Hh - 1);
  int i00 = cy0 * Ww + cx0, i01 = cy0 * Ww + cx1;
  int i10 = cy1 * Ww + cx0, i11 = cy1 * Ww + cx1;
  int c = lane;
  if (c < 48){
    const float* r00 = xnc + ((size_t)(b * Nn + i00)) * 48;
    const float* r01 = xnc + ((size_t)(b * Nn + i01)) * 48;
    const float* r10 = xnc + ((size_t)(b * Nn + i10)) * 48;
    const float* r11 = xnc + ((size_t)(b * Nn + i11)) * 48;
    rowb[wv][c] = w00 * r00[c] + w01 * r01[c] + w10 * r10[c] + w11 * r11[c];
  }
  // same-wave LDS RAW: compiler inserts lgkmcnt; no barrier needed
  int o = lane;
  if (o < 48){
    float ka = bk[o], va = bv[o];
    #pragma unroll
    for (int cc = 0; cc < 48; cc++){
      float r = rowb[wv][cc];                 // broadcast
      ka = fmaf(wkt[cc][o], r, ka);           // conflict-free (pad 49)
      va = fmaf(wvt[cc][o], r, va);
    }
    kk_bf[(size_t)idx * 64 + o] = (bf16)ka;                  // coalesced
    vt_bf[((size_t)(b * Cch + o)) * Nn + n] = (bf16)va;      // 48-CL scatter, 1 instr
  }
  if (o < 16) kk_bf[(size_t)idx * 64 + 48 + o] = (bf16)0.f;  // zero-pad
}

// ---------------- K4: MFMA flash attention, split-K=2, NO max-subtraction ----
// (unchanged from R10: 102 us)
__global__ __launch_bounds__(256, 3) void k_attn(const bf16* __restrict__ q_bf,
                                              const bf16* __restrict__ kk_bf,
                                              const bf16* __restrict__ vt_bf,
                                              const float2* __restrict__ axay,
                                              const float* __restrict__ rpe,
                                              float* __restrict__ o_part,
                                              float* __restrict__ s_part){
  __shared__ __align__(16) bf16 ks[128][72];
  __shared__ __align__(16) bf16 vt[48][136];
  __shared__ __align__(16) bf16 ps[16][136];
  __shared__ __align__(16) float g[128][26];     // blended RPE rows
  __shared__ float axs[128], wy0s[128], wy1s[128];
  __shared__ int xlos[128], r0s[128], r1s[128];

  const int tid = threadIdx.x;
  const int b  = blockIdx.x >> 9;
  const int kp = (blockIdx.x >> 8) & 1;
  const int m0 = (blockIdx.x & 255) * 16;
  const int wid = tid >> 6, lane = tid & 63;
  const int q16 = lane >> 4, l16 = lane & 15;
  const int wn0 = wid * 32;

  const bf16* qb = q_bf + ((size_t)(b * Nn + m0 + l16)) * 64;
  bf16x8 qf0 = *(const bf16x8*)(qb + q16 * 8);
  bf16x8 qf1 = *(const bf16x8*)(qb + 32 + q16 * 8);

  const float qgy = (float)(m0 >> 6) * (2.f / 63.f) - 1.f;
  const float byq = 47.5f * qgy;              // gyr = ay + byq
  const float scale = 0.14433756729740643f;   // 48^-0.5
  const float bx0 = 47.5f * ((float)(m0 & 63) * (2.f / 63.f) - 1.f);
  float bxr[4];
  #pragma unroll
  for (int r = 0; r < 4; r++){
    int mcol = (m0 & 63) + q16 * 4 + r;
    bxr[r] = 47.5f * ((float)mcol * (2.f / 63.f) - 1.f);
  }

  f32x4 oacc[3];
  #pragma unroll
  for (int ct = 0; ct < 3; ct++) oacc[ct] = (f32x4){0.f, 0.f, 0.f, 0.f};
  float s_runw[4] = {0.f, 0.f, 0.f, 0.f};   // wave-partial plain denominators

  for (int chk = 0; chk < 16; chk++){
    const int n0 = kp * 2048 + chk * 128;
    __syncthreads();                               // A: tiles/params free
    const bf16* kg = kk_bf + (size_t)(b * Nn + n0) * 64;
    #pragma unroll
    for (int j = 0; j < 4; j++){
      int f = tid + j * 256;
      int r = f >> 3, c8 = (f & 7) * 8;
      *(bf16x8*)&ks[r][c8] = *(const bf16x8*)(kg + r * 64 + c8);
    }
    const bf16* vg = vt_bf + (size_t)b * Cch * Nn + n0;
    #pragma unroll
    for (int j = 0; j < 3; j++){
      int f = tid + j * 256;
      int r = f >> 4, c8 = (f & 15) * 8;
      *(bf16x8*)&vt[r][c8] = *(const bf16x8*)(vg + (size_t)r * Nn + c8);
    }
    if (tid < 128){
      float2 aa = axay[(size_t)b * Nn + n0 + tid];  // (ay, ax)
      float gyr = aa.x + byq;
      float y0f = floorf(gyr);
      float wy = gyr - y0f;
      int y0 = (int)y0f, y1 = y0 + 1;
      wy0s[tid] = ((unsigned)y0 < 191u) ? (1.f - wy) : 0.f;
      wy1s[tid] = ((unsigned)y1 < 191u) ? wy : 0.f;
      r0s[tid] = min(max(y0, 0), 190) * 191;
      r1s[tid] = min(max(y1, 0), 190) * 191;
      axs[tid] = aa.y;
      xlos[tid] = (int)floorf(aa.y + bx0);
    }
    __syncthreads();                               // B: tiles + params ready
    // g-build: wave's own 32 keys, independent coalesced rpe loads
    {
      int s = lane >> 5, jj = lane & 31;
      if (jj < 26){
        #pragma unroll
        for (int it = 0; it < 16; it++){
          int n = wn0 + it * 2 + s;
          int cx = min(max(xlos[n] + jj, 0), 190);
          g[n][jj] = wy0s[n] * rpe[r0s[n] + cx] + wy1s[n] * rpe[r1s[n] + cx];
        }
      }
    }
    // QK^T MFMA: wave's 32 keys
    f32x4 s0 = (f32x4){0.f, 0.f, 0.f, 0.f};
    f32x4 s1 = (f32x4){0.f, 0.f, 0.f, 0.f};
    {
      const bf16* kr0 = &ks[wn0 + l16][q16 * 8];
      const bf16* kr1 = &ks[wn0 + 16 + l16][q16 * 8];
      bf16x8 b00 = *(const bf16x8*)kr0;
      bf16x8 b01 = *(const bf16x8*)(kr0 + 32);
      bf16x8 b10 = *(const bf16x8*)kr1;
      bf16x8 b11 = *(const bf16x8*)(kr1 + 32);
      s0 = __builtin_amdgcn_mfma_f32_16x16x32_bf16(qf0, b00, s0, 0, 0, 0);
      s0 = __builtin_amdgcn_mfma_f32_16x16x32_bf16(qf1, b01, s0, 0, 0, 0);
      s1 = __builtin_amdgcn_mfma_f32_16x16x32_bf16(qf0, b10, s1, 0, 0, 0);
      s1 = __builtin_amdgcn_mfma_f32_16x16x32_bf16(qf1, b11, s1, 0, 0, 0);
    }
    // bias + exp directly (no max-sub), accumulate row partial sums
    float rs[4] = {0.f, 0.f, 0.f, 0.f};
    #pragma unroll
    for (int nt = 0; nt < 2; nt++){
      int nl = wn0 + nt * 16 + l16;
      float ax = axs[nl];
      int xb = xlos[nl];
      f32x4 sv = nt ? s1 : s0;
      #pragma unroll
      for (int r = 0; r < 4; r++){
        float gxr = ax + bxr[r];
        float x0f = floorf(gxr);
        float wx = gxr - x0f;
        int x0 = (int)x0f;
        float wx0 = ((unsigned)x0 < 191u) ? (1.f - wx) : 0.f;
        float wx1 = ((unsigned)(x0 + 1) < 191u) ? wx : 0.f;
        int j0 = min(max(x0 - xb, 0), 24);
        float bias = wx0 * g[nl][j0] + wx1 * g[nl][j0 + 1];
        float e = __expf(fmaf(sv[r], scale, bias));
        rs[r] += e;
        ps[q16 * 4 + r][nl] = (bf16)e;
      }
    }
    #pragma unroll
    for (int r = 0; r < 4; r++){
      float v = rs[r];
      #pragma unroll
      for (int msk = 1; msk < 16; msk <<= 1) v += __shfl_xor(v, msk);
      s_runw[r] += v;
    }
    // PV MFMA: wave's own 32 P-columns (same-wave LDS, no barrier)
    {
      bf16x8 pa = *(const bf16x8*)&ps[l16][wn0 + q16 * 8];
      #pragma unroll
      for (int ct = 0; ct < 3; ct++){
        bf16x8 vb = *(const bf16x8*)&vt[ct * 16 + l16][wn0 + q16 * 8];
        oacc[ct] = __builtin_amdgcn_mfma_f32_16x16x32_bf16(pa, vb, oacc[ct], 0, 0, 0);
      }
    }
  }
  // epilogue: cross-wave plain sums -> o_part[b][kp][c][m], s_part
  __syncthreads();
  float* ored = (float*)ks;        // [4][16][48] f32 = 12288 B
  float* sred = (float*)vt;        // [4][16]
  #pragma unroll
  for (int ct = 0; ct < 3; ct++)
    #pragma unroll
    for (int r = 0; r < 4; r++)
      ored[(wid * 16 + q16 * 4 + r) * 48 + ct * 16 + l16] = oacc[ct][r];
  if (l16 == 0){
    #pragma unroll
    for (int r = 0; r < 4; r++) sred[wid * 16 + q16 * 4 + r] = s_runw[r];
  }
  __syncthreads();
  size_t obase = ((size_t)(b * 2 + kp) * Cch) * Nn;
  #pragma unroll
  for (int e = 0; e < 3; e++){
    int idx = tid + e * 256;         // 768 = 48c x 16m
    int c = idx >> 4, mm = idx & 15;
    float v = ored[mm * 48 + c] + ored[(16 + mm) * 48 + c]
            + ored[(32 + mm) * 48 + c] + ored[(48 + mm) * 48 + c];
    o_part[obase + (size_t)c * Nn + m0 + mm] = v;
  }
  if (tid < 16)
    s_part[(size_t)(b * 2 + kp) * Nn + m0 + tid] =
        sred[tid] + sred[16 + tid] + sred[32 + tid] + sred[48 + tid];
}

// ---------------- K5: MFMA window attention; stages from xnc, out (B,N,C) ----
__global__ __launch_bounds__(256) void k_win(const float* __restrict__ xnc,
                                             const float* __restrict__ iw,
                                             const float* __restrict__ ib,
                                             const float* __restrict__ bng,
                                             const float* __restrict__ bnb,
                                             const float* __restrict__ bnm,
                                             const float* __restrict__ bnv,
                                             float* __restrict__ wout_nc){
  __shared__ __align__(16) bf16 xs[64][72];
  __shared__ __align__(16) bf16 wtt[32][72];
  __shared__ __align__(16) bf16 qs[64][72];    // cols 0..15 q, 16..31 zero
  __shared__ __align__(16) bf16 vst[16][72];   // v transposed [ch][token]
  __shared__ __align__(16) bf16 psw[64][72];
  __shared__ float bnsc[32], bnsh[32];
  int s = blockIdx.x >> 7;
  int r7 = blockIdx.x & 127;
  int b = r7 >> 6, wi = r7 & 63;
  int tid = threadIdx.x;
  int wid = tid >> 6, lane = tid & 63;
  int q16 = lane >> 4, l16 = lane & 15;
  // stage x tile from xnc rows (row-contiguous -> coalesced)
  for (int f = tid; f < 64 * 48; f += 256){
    int t = f / 48, c = f - t * 48;
    int p = (s == 0) ? (((wi >> 3) * 8 + (t >> 3)) * 64 + (wi & 7) * 8 + (t & 7))
          : (s == 1) ? (t * 64 + wi) : (wi * 64 + t);
    xs[t][c] = (bf16)xnc[((size_t)(b * Nn + p)) * 48 + c];
  }
  for (int f = tid; f < 64 * 16; f += 256){
    int t = f >> 4, j = f & 15;
    xs[t][48 + j] = (bf16)0.f;
    qs[t][16 + j] = (bf16)0.f;
  }
  for (int f = tid; f < 32 * 64; f += 256){
    int o = f >> 6, c = f & 63;
    wtt[o][c] = (c < 48) ? (bf16)iw[(s * 32 + o) * 48 + c] : (bf16)0.f;
  }
  if (tid < 32){
    int ch = s * 32 + tid;
    float sc = bng[ch] * rsqrtf(bnv[ch] + 1e-5f);
    bnsc[tid] = sc;
    bnsh[tid] = (ib[ch] - bnm[ch]) * sc + bnb[ch];
  }
  __syncthreads();
  // proj: wave wid -> token rows wid*16..; nt=0 -> q channels, nt=1 -> v
  {
    bf16x8 a0 = *(const bf16x8*)&xs[wid * 16 + l16][q16 * 8];
    bf16x8 a1 = *(const bf16x8*)&xs[wid * 16 + l16][32 + q16 * 8];
    #pragma unroll
    for (int nt = 0; nt < 2; nt++){
      bf16x8 b0 = *(const bf16x8*)&wtt[nt * 16 + l16][q16 * 8];
      bf16x8 b1 = *(const bf16x8*)&wtt[nt * 16 + l16][32 + q16 * 8];
      f32x4 acc = (f32x4){0.f, 0.f, 0.f, 0.f};
      acc = __builtin_amdgcn_mfma_f32_16x16x32_bf16(a0, b0, acc, 0, 0, 0);
      acc = __builtin_amdgcn_mfma_f32_16x16x32_bf16(a1, b1, acc, 0, 0, 0);
      float scv = bnsc[nt * 16 + l16], shv = bnsh[nt * 16 + l16];
      #pragma unroll
      for (int r = 0; r < 4; r++){
        float v = fmaf(acc[r], scv, shv);
        int tok = wid * 16 + q16 * 4 + r;
        if (nt == 0) qs[tok][l16] = (bf16)v;       // C-layout: col=channel
        else         vst[l16][tok] = (bf16)v;      // transposed
      }
    }
  }
  __syncthreads();
  // S = q q^T (16 tiles; wave does its 4 row-tiles), softmax per row
  f32x4 sreg[4];
  {
    bf16x8 aq = *(const bf16x8*)&qs[wid * 16 + l16][q16 * 8];
    #pragma unroll
    for (int nt = 0; nt < 4; nt++){
      bf16x8 bq = *(const bf16x8*)&qs[nt * 16 + l16][q16 * 8];
      f32x4 acc = (f32x4){0.f, 0.f, 0.f, 0.f};
      sreg[nt] = __builtin_amdgcn_mfma_f32_16x16x32_bf16(aq, bq, acc, 0, 0, 0);
    }
  }
  float rinv[4];
  #pragma unroll
  for (int r = 0; r < 4; r++){
    float mx = fmaxf(fmaxf(sreg[0][r], sreg[1][r]), fmaxf(sreg[2][r], sreg[3][r]));
    #pragma unroll
    for (int msk = 1; msk < 16; msk <<= 1) mx = fmaxf(mx, __shfl_xor(mx, msk));
    float sum = 0.f;
    #pragma unroll
    for (int nt = 0; nt < 4; nt++){
      float e = __expf(sreg[nt][r] - mx);
      sum += e;
      psw[wid * 16 + q16 * 4 + r][nt * 16 + l16] = (bf16)e;
    }
    #pragma unroll
    for (int msk = 1; msk < 16; msk <<= 1) sum += __shfl_xor(sum, msk);
    rinv[r] = 1.f / sum;
  }
  // PV: O = P @ V, wave's 16 tokens (psw same-wave; vst synced above)
  f32x4 oac = (f32x4){0.f, 0.f, 0.f, 0.f};
  {
    bf16x8 pa0 = *(const bf16x8*)&psw[wid * 16 + l16][q16 * 8];
    bf16x8 pa1 = *(const bf16x8*)&psw[wid * 16 + l16][32 + q16 * 8];
    bf16x8 vb0 = *(const bf16x8*)&vst[l16][q16 * 8];
    bf16x8 vb1 = *(const bf16x8*)&vst[l16][32 + q16 * 8];
    oac = __builtin_amdgcn_mfma_f32_16x16x32_bf16(pa0, vb0, oac, 0, 0, 0);
    oac = __builtin_amdgcn_mfma_f32_16x16x32_bf16(pa1, vb1, oac, 0, 0, 0);
  }
  #pragma unroll
  for (int r = 0; r < 4; r++){
    int tok = wid * 16 + q16 * 4 + r;
    int p = (s == 0) ? (((wi >> 3) * 8 + (tok >> 3)) * 64 + (wi & 7) * 8 + (tok & 7))
          : (s == 1) ? (tok * 64 + wi) : (wi * 64 + tok);
    wout_nc[((size_t)(b * Nn + p)) * 48 + s * 16 + l16] = oac[r] * rinv[r];
  }
}

// ---------------- K6: thread-per-pixel pout conv + merge + mix ---------------
// wout read ONCE per element (row-major); o_part/s_part/out coalesced per o.
__global__ __launch_bounds__(128) void k_final(const float* __restrict__ wout_nc,
                        const float* __restrict__ pw,
                        const float* __restrict__ pb, const float* __restrict__ o_part,
                        const float* __restrict__ s_part, float* __restrict__ out){
  __shared__ float pwT[2304];          // pwT[c*48+o]
  int tid = threadIdx.x;
  for (int f = tid; f < 2304; f += 128){
    int o = f / 48, c = f - o * 48;
    pwT[c * 48 + o] = pw[f];
  }
  __syncthreads();
  int idx = blockIdx.x * 128 + tid;
  int b = idx >> 12, p = idx & (Nn - 1);
  float winrow[48];
  const float4* wr4 = (const float4*)(wout_nc + (size_t)idx * 48);
  #pragma unroll
  for (int j = 0; j < 12; j++){
    float4 v = wr4[j];
    winrow[j * 4 + 0] = v.x; winrow[j * 4 + 1] = v.y;
    winrow[j * 4 + 2] = v.z; winrow[j * 4 + 3] = v.w;
  }
  float acc[48];
  #pragma unroll
  for (int o = 0; o < 48; o++) acc[o] = pb[o];
  #pragma unroll
  for (int c = 0; c < 48; c++){
    float xv = winrow[c];
    const float4* wr = (const float4*)&pwT[c * 48];
    #pragma unroll
    for (int j = 0; j < 12; j++){
      float4 w = wr[j];                  // broadcast
      acc[j * 4 + 0] = fmaf(xv, w.x, acc[j * 4 + 0]);
      acc[j * 4 + 1] = fmaf(xv, w.y, acc[j * 4 + 1]);
      acc[j * 4 + 2] = fmaf(xv, w.z, acc[j * 4 + 2]);
      acc[j * 4 + 3] = fmaf(xv, w.w, acc[j * 4 + 3]);
    }
  }
  float sden = s_part[(size_t)(b * 2) * Nn + p] + s_part[(size_t)(b * 2 + 1) * Nn + p];
  float rinv = 0.5f / sden;
  const float* op0 = o_part + (size_t)(b * 2) * Cch * Nn + p;
  const float* op1 = o_part + (size_t)(b * 2 + 1) * Cch * Nn + p;
  float* op = out + (size_t)b * Cch * Nn + p;
  #pragma unroll
  for (int o = 0; o < 48; o++){
    float odv = (op0[(size_t)o * Nn] + op1[(size_t)o * Nn]) * rinv;  // coalesced
    op[(size_t)o * Nn] = 0.5f * acc[o] + odv;                        // coalesced
  }
}

extern "C" void kernel_launch(void* const* d_in, const int* in_sizes, int n_in,
                              void* d_out, int out_size, void* d_ws, size_t ws_size,
                              hipStream_t stream){
  const float* x   = (const float*)d_in[0];
  const float* Wq  = (const float*)d_in[1];
  const float* bq  = (const float*)d_in[2];
  const float* dww = (const float*)d_in[3];
  const float* dwb = (const float*)d_in[4];
  const float* lng = (const float*)d_in[5];
  const float* lnb = (const float*)d_in[6];
  const float* pww = (const float*)d_in[7];
  const float* Wk  = (const float*)d_in[8];
  const float* bk  = (const float*)d_in[9];
  const float* Wv  = (const float*)d_in[10];
  const float* bv  = (const float*)d_in[11];
  const float* iw  = (const float*)d_in[12];
  const float* ib  = (const float*)d_in[13];
  const float* bng = (const float*)d_in[14];
  const float* bnb = (const float*)d_in[15];
  const float* bnm = (const float*)d_in[16];
  const float* bnv = (const float*)d_in[17];
  const float* pw  = (const float*)d_in[18];
  const float* pb  = (const float*)d_in[19];
  const float* rpe = (const float*)d_in[20];

  // Workspace (f32-slot offsets). qnc aliases o_part[0,393216): qnc dead after
  // k_offset_pos, o_part written later by k_attn.
  float*  ws     = (float*)d_ws;
  float*  qnc    = ws;                    // [0,       393216)  dead after K2
  float*  o_part = ws;                    // [0,       786432)
  float*  pos    = ws + 786432;           // [786432,  802816)
  float2* axay   = (float2*)(ws + 802816);// 8192 float2 -> [802816, 819200)
  float*  wout   = ws + 819200;           // (B,N,C)     [819200, 1212416)
  bf16*   q_bf   = (bf16*)(ws + 1212416); // 524288 bf16 -> [1212416,1474560)
  bf16*   kk_bf  = (bf16*)(ws + 1474560); // 524288 bf16 -> [1474560,1736704)
  bf16*   vt_bf  = (bf16*)(ws + 1736704); // 393216 bf16 -> [1736704,1933312)
  float*  s_part = ws + 1933312;          // [1933312,1949696)
  float*  xnc    = ws + 1949696;          // (B,N,C)     [1949696,2342912) = 9.37MB
  float*  out    = (float*)d_out;

  k_conv1x1   <<<(Bsz * Nn) / 128, 128, 0, stream>>>(x, Wq, bq, qnc, q_bf, xnc);
  k_offset_pos<<<(Bsz * Nn) / 4, 256, 0, stream>>>(qnc, dww, dwb, lng, lnb, pww, pos);
  k_samplekv  <<<(Bsz * Nn) / 8, 512, 0, stream>>>(xnc, pos, Wk, bk, Wv, bv,
                                                   kk_bf, vt_bf, axay);
  k_attn      <<<Bsz * 512, 256, 0, stream>>>(q_bf, kk_bf, vt_bf, axay, rpe,
                                              o_part, s_part);
  k_win       <<<384, 256, 0, stream>>>(xnc, iw, ib, bng, bnb, bnm, bnv, wout);
  k_final     <<<(Bsz * Nn) / 128, 128, 0, stream>>>(wout, pw, pb, o_part,
                                                     s_part, out);
}

// Round 12
// 206.377 us; speedup vs baseline: 1.1931x; 1.1931x over previous
//
#include <hip/hip_runtime.h>
#include <hip/hip_bf16.h>
#include <math.h>

#define Bsz 2
#define Cch 48
#define Hh 64
#define Ww 64
#define Nn 4096

typedef __bf16 bf16;
typedef __attribute__((ext_vector_type(8))) __bf16 bf16x8;
typedef __attribute__((ext_vector_type(4))) float f32x4;

// ---------------- K1: conv1x1 -> qnc (B,N,48) fp32 + q_bf (B,N,64) bf16 -----
// (R10 version: 393K threads, L2-resident re-reads, full latency hiding)
__global__ void k_conv1x1(const float* __restrict__ in, const float* __restrict__ Wt,
                          const float* __restrict__ bias, float* __restrict__ qnc,
                          bf16* __restrict__ qbf){
  int chunk = blockIdx.x & 15;            // N/256 = 16 chunks
  int o = (blockIdx.x >> 4) % Cch;
  int b = blockIdx.x / (16 * Cch);
  int p = chunk * 256 + threadIdx.x;
  float acc = bias[o];
  const float* ip = in + (b * Cch) * Nn + p;
  const float* wp = Wt + o * Cch;
  #pragma unroll
  for (int c = 0; c < Cch; c++) acc += wp[c] * ip[c * Nn];
  qnc[((size_t)(b * Nn + p)) * 48 + o] = acc;
  size_t qb = ((size_t)(b * Nn + p)) * 64;
  qbf[qb + o] = (bf16)acc;
  if (o < 16) qbf[qb + 48 + o] = (bf16)0.f;   // zero-pad k=48..63
}

// ---------------- K2: wave-per-pixel dw3x3 + LN + GELU + pw + tanh -> pos ----
__global__ __launch_bounds__(256) void k_offset_pos(const float* __restrict__ qnc,
                             const float* __restrict__ dww,
                             const float* __restrict__ dwb, const float* __restrict__ lng,
                             const float* __restrict__ lnb, const float* __restrict__ pww,
                             float* __restrict__ pos){
  int wv = threadIdx.x >> 6, lane = threadIdx.x & 63;
  int idx = blockIdx.x * 4 + wv;          // (b,pixel)
  int b = idx >> 12;
  int p = idx & (Nn - 1);
  int y = p >> 6, x = p & 63;
  int c = lane;
  float t = 0.f;
  if (c < 48){
    t = dwb[c];
    #pragma unroll
    for (int ky = -1; ky <= 1; ky++){
      int yy = y + ky;
      if (yy < 0 || yy >= Hh) continue;          // wave-uniform branch
      #pragma unroll
      for (int kx = -1; kx <= 1; kx++){
        int xx = x + kx;
        if (xx < 0 || xx >= Ww) continue;        // wave-uniform branch
        t = fmaf(qnc[((size_t)(b * Nn + yy * Ww + xx)) * 48 + c],
                 dww[c * 9 + (ky + 1) * 3 + (kx + 1)], t);
      }
    }
  }
  float s = t;
  #pragma unroll
  for (int m = 1; m < 64; m <<= 1) s += __shfl_xor(s, m);
  float mean = s * (1.f / 48.f);
  float d = (c < 48) ? (t - mean) : 0.f;
  float v = d * d;
  #pragma unroll
  for (int m = 1; m < 64; m <<= 1) v += __shfl_xor(v, m);
  float rstd = rsqrtf(v * (1.f / 48.f) + 1e-5f);
  float p0 = 0.f, p1 = 0.f;
  if (c < 48){
    float u = (t - mean) * rstd * lng[c] + lnb[c];
    u = 0.5f * u * (1.f + erff(u * 0.70710678118654752f));   // exact gelu
    p0 = pww[c] * u;
    p1 = pww[48 + c] * u;
  }
  #pragma unroll
  for (int m = 1; m < 64; m <<= 1){ p0 += __shfl_xor(p0, m); p1 += __shfl_xor(p1, m); }
  if (lane == 0){
    float posy = tanhf(p0) * (2.f / 63.f) + ((0.5f + (float)y) * (2.f / 63.f) - 1.f);
    float posx = tanhf(p1) * (2.f / 63.f) + ((0.5f + (float)x) * (2.f / 63.f) - 1.f);
    pos[idx * 2 + 0] = posy;
    pos[idx * 2 + 1] = posx;
  }
}

// ---------------- K3: wave-per-key fused sample + k,v projection (R10) -------
__global__ __launch_bounds__(512) void k_samplekv(const float* __restrict__ x,
                           const float* __restrict__ pos,
                           const float* __restrict__ Wk, const float* __restrict__ bk,
                           const float* __restrict__ Wv, const float* __restrict__ bv,
                           bf16* __restrict__ kk_bf, bf16* __restrict__ vt_bf,
                           float2* __restrict__ axay){
  __shared__ float wkt[48][49];   // wkt[c][o] = Wk[o][c]
  __shared__ float wvt[48][49];
  __shared__ float rowb[8][48];
  int tid = threadIdx.x;
  for (int f = tid; f < 2304; f += 512){
    int o = f / 48, c = f - o * 48;
    wkt[c][o] = Wk[f];
    wvt[c][o] = Wv[f];
  }
  __syncthreads();
  int wv = tid >> 6, lane = tid & 63;
  int idx = blockIdx.x * 8 + wv;
  int b = idx >> 12;
  int n = idx & (Nn - 1);
  float py = pos[idx * 2], px = pos[idx * 2 + 1];
  if (lane == 0) axay[idx] = make_float2(95.f - 47.5f * py, 95.f - 47.5f * px);
  float gx = (px + 1.f) * 0.5f * 63.f;
  float gy = (py + 1.f) * 0.5f * 63.f;
  float x0f = floorf(gx), y0f = floorf(gy);
  float wx = gx - x0f, wy = gy - y0f;
  int x0 = (int)x0f, y0 = (int)y0f, x1 = x0 + 1, y1 = y0 + 1;
  float w00 = (1.f - wy) * (1.f - wx), w01 = (1.f - wy) * wx;
  float w10 = wy * (1.f - wx),         w11 = wy * wx;
  bool vx0 = (x0 >= 0) && (x0 < Ww), vx1 = (x1 >= 0) && (x1 < Ww);
  bool vy0 = (y0 >= 0) && (y0 < Hh), vy1 = (y1 >= 0) && (y1 < Hh);
  if (!(vx0 && vy0)) w00 = 0.f;
  if (!(vx1 && vy0)) w01 = 0.f;
  if (!(vx0 && vy1)) w10 = 0.f;
  if (!(vx1 && vy1)) w11 = 0.f;
  int cx0 = min(max(x0, 0), Ww - 1), cx1 = min(max(x1, 0), Ww - 1);
  int cy0 = min(max(y0, 0), Hh - 1), cy1 = min(max(y1, 0), Hh - 1);
  int i00 = cy0 * Ww + cx0, i01 = cy0 * Ww + cx1;
  int i10 = cy1 * Ww + cx0, i11 = cy1 * Ww + cx1;
  int c = lane;
  if (c < 48){
    const float* xc = x + ((size_t)(b * Cch + c)) * Nn;
    rowb[wv][c] = w00 * xc[i00] + w01 * xc[i01] + w10 * xc[i10] + w11 * xc[i11];
  }
  // same-wave LDS RAW: compiler inserts lgkmcnt; no barrier needed
  int o = lane;
  if (o < 48){
    float ka = bk[o], va = bv[o];
    #pragma unroll
    for (int cc = 0; cc < 48; cc++){
      float r = rowb[wv][cc];                 // broadcast
      ka = fmaf(wkt[cc][o], r, ka);           // conflict-free (pad 49)
      va = fmaf(wvt[cc][o], r, va);
    }
    kk_bf[(size_t)idx * 64 + o] = (bf16)ka;                  // coalesced
    vt_bf[((size_t)(b * Cch + o)) * Nn + n] = (bf16)va;      // 48-CL scatter, 1 instr
  }
  if (o < 16) kk_bf[(size_t)idx * 64 + 48 + o] = (bf16)0.f;  // zero-pad
}

// ---------------- K4: MFMA flash attention — BARRIER-FREE chunk loop ---------
// Waves own disjoint 32-key ranges, so K/V LDS staging was pure overhead:
// B-fragments now load DIRECTLY from global (L2-hot; identical address set).
// Bilinear params computed per-wave (lane<32 -> own keys), g and ps are
// same-wave -> zero __syncthreads() in the 16-chunk loop; waves fully
// independent, loads pipeline across chunks. LDS 20.7KB -> 4 blocks/CU.
__global__ __launch_bounds__(256, 4) void k_attn(const bf16* __restrict__ q_bf,
                                              const bf16* __restrict__ kk_bf,
                                              const bf16* __restrict__ vt_bf,
                                              const float2* __restrict__ axay,
                                              const float* __restrict__ rpe,
                                              float* __restrict__ o_part,
                                              float* __restrict__ s_part){
  __shared__ __align__(16) float g[128][26];     // blended RPE rows (per-wave cols)
  __shared__ float axs[128], wy0s[128], wy1s[128];
  __shared__ int xlos[128], r0s[128], r1s[128];
  __shared__ __align__(16) bf16 ps[16][136];     // probs; per-wave column ranges

  const int tid = threadIdx.x;
  const int b  = blockIdx.x >> 9;
  const int kp = (blockIdx.x >> 8) & 1;
  const int m0 = (blockIdx.x & 255) * 16;
  const int wid = tid >> 6, lane = tid & 63;
  const int q16 = lane >> 4, l16 = lane & 15;
  const int wn0 = wid * 32;

  const bf16* qb = q_bf + ((size_t)(b * Nn + m0 + l16)) * 64;
  bf16x8 qf0 = *(const bf16x8*)(qb + q16 * 8);
  bf16x8 qf1 = *(const bf16x8*)(qb + 32 + q16 * 8);

  const float qgy = (float)(m0 >> 6) * (2.f / 63.f) - 1.f;
  const float byq = 47.5f * qgy;              // gyr = ay + byq
  const float scale = 0.14433756729740643f;   // 48^-0.5
  const float bx0 = 47.5f * ((float)(m0 & 63) * (2.f / 63.f) - 1.f);
  float bxr[4];
  #pragma unroll
  for (int r = 0; r < 4; r++){
    int mcol = (m0 & 63) + q16 * 4 + r;
    bxr[r] = 47.5f * ((float)mcol * (2.f / 63.f) - 1.f);
  }

  f32x4 oacc[3];
  #pragma unroll
  for (int ct = 0; ct < 3; ct++) oacc[ct] = (f32x4){0.f, 0.f, 0.f, 0.f};
  float s_runw[4] = {0.f, 0.f, 0.f, 0.f};   // wave-partial plain denominators

  for (int chk = 0; chk < 16; chk++){
    const int n0 = kp * 2048 + chk * 128;
    // ---- per-wave bilinear params: lane<32 handles key wn0+lane ----
    if (lane < 32){
      int n = wn0 + lane;
      float2 aa = axay[(size_t)b * Nn + n0 + n];  // (ay, ax) coalesced
      float gyr = aa.x + byq;
      float y0f = floorf(gyr);
      float wy = gyr - y0f;
      int y0 = (int)y0f, y1 = y0 + 1;
      wy0s[n] = ((unsigned)y0 < 191u) ? (1.f - wy) : 0.f;
      wy1s[n] = ((unsigned)y1 < 191u) ? wy : 0.f;
      r0s[n] = min(max(y0, 0), 190) * 191;
      r1s[n] = min(max(y1, 0), 190) * 191;
      axs[n] = aa.y;
      xlos[n] = (int)floorf(aa.y + bx0);
    }
    // ---- g-build: wave's own 32 keys (same-wave params RAW) ----
    {
      int s = lane >> 5, jj = lane & 31;
      if (jj < 26){
        #pragma unroll
        for (int it = 0; it < 16; it++){
          int n = wn0 + it * 2 + s;
          int cx = min(max(xlos[n] + jj, 0), 190);
          g[n][jj] = wy0s[n] * rpe[r0s[n] + cx] + wy1s[n] * rpe[r1s[n] + cx];
        }
      }
    }
    // ---- QK^T MFMA: B-fragments direct from global (L2-hot) ----
    f32x4 s0 = (f32x4){0.f, 0.f, 0.f, 0.f};
    f32x4 s1 = (f32x4){0.f, 0.f, 0.f, 0.f};
    {
      const bf16* kg = kk_bf + (size_t)(b * Nn + n0 + wn0 + l16) * 64;
      bf16x8 b00 = *(const bf16x8*)(kg + q16 * 8);
      bf16x8 b01 = *(const bf16x8*)(kg + 32 + q16 * 8);
      bf16x8 b10 = *(const bf16x8*)(kg + 16 * 64 + q16 * 8);
      bf16x8 b11 = *(const bf16x8*)(kg + 16 * 64 + 32 + q16 * 8);
      s0 = __builtin_amdgcn_mfma_f32_16x16x32_bf16(qf0, b00, s0, 0, 0, 0);
      s0 = __builtin_amdgcn_mfma_f32_16x16x32_bf16(qf1, b01, s0, 0, 0, 0);
      s1 = __builtin_amdgcn_mfma_f32_16x16x32_bf16(qf0, b10, s1, 0, 0, 0);
      s1 = __builtin_amdgcn_mfma_f32_16x16x32_bf16(qf1, b11, s1, 0, 0, 0);
    }
    // ---- bias + exp (no max-sub; logits bounded), ps write same-wave ----
    float rs[4] = {0.f, 0.f, 0.f, 0.f};
    #pragma unroll
    for (int nt = 0; nt < 2; nt++){
      int nl = wn0 + nt * 16 + l16;
      float ax = axs[nl];
      int xb = xlos[nl];
      f32x4 sv = nt ? s1 : s0;
      #pragma unroll
      for (int r = 0; r < 4; r++){
        float gxr = ax + bxr[r];
        float x0f = floorf(gxr);
        float wx = gxr - x0f;
        int x0 = (int)x0f;
        float wx0 = ((unsigned)x0 < 191u) ? (1.f - wx) : 0.f;
        float wx1 = ((unsigned)(x0 + 1) < 191u) ? wx : 0.f;
        int j0 = min(max(x0 - xb, 0), 24);
        float bias = wx0 * g[nl][j0] + wx1 * g[nl][j0 + 1];
        float e = __expf(fmaf(sv[r], scale, bias));
        rs[r] += e;
        ps[q16 * 4 + r][nl] = (bf16)e;
      }
    }
    #pragma unroll
    for (int r = 0; r < 4; r++){
      float v = rs[r];
      #pragma unroll
      for (int msk = 1; msk < 16; msk <<= 1) v += __shfl_xor(v, msk);
      s_runw[r] += v;
    }
    // ---- PV MFMA: A=ps (same-wave), B=V direct from global ----
    {
      bf16x8 pa = *(const bf16x8*)&ps[l16][wn0 + q16 * 8];
      const bf16* vgb = vt_bf + (size_t)(b * Cch + l16) * Nn + n0 + wn0 + q16 * 8;
      #pragma unroll
      for (int ct = 0; ct < 3; ct++){
        bf16x8 vb = *(const bf16x8*)(vgb + (size_t)(ct * 16) * Nn);
        oacc[ct] = __builtin_amdgcn_mfma_f32_16x16x32_bf16(pa, vb, oacc[ct], 0, 0, 0);
      }
    }
  }
  // ---- epilogue: cross-wave plain sums (scratch aliases g/axs) ----
  __syncthreads();                 // all waves done with g/params
  float* ored = (float*)g;         // 64x48 f32 = 12288 B <= 13312
  float* sred = axs;               // 64 floats
  #pragma unroll
  for (int ct = 0; ct < 3; ct++)
    #pragma unroll
    for (int r = 0; r < 4; r++)
      ored[(wid * 16 + q16 * 4 + r) * 48 + ct * 16 + l16] = oacc[ct][r];
  if (l16 == 0){
    #pragma unroll
    for (int r = 0; r < 4; r++) sred[wid * 16 + q16 * 4 + r] = s_runw[r];
  }
  __syncthreads();
  size_t obase = ((size_t)(b * 2 + kp) * Cch) * Nn;
  #pragma unroll
  for (int e = 0; e < 3; e++){
    int idx = tid + e * 256;         // 768 = 48c x 16m
    int c = idx >> 4, mm = idx & 15;
    float v = ored[mm * 48 + c] + ored[(16 + mm) * 48 + c]
            + ored[(32 + mm) * 48 + c] + ored[(48 + mm) * 48 + c];
    o_part[obase + (size_t)c * Nn + m0 + mm] = v;
  }
  if (tid < 16)
    s_part[(size_t)(b * 2 + kp) * Nn + m0 + tid] =
        sred[tid] + sred[16 + tid] + sred[32 + tid] + sred[48 + tid];
}

// ---------------- K5: MFMA window attention (R10), x (B,C,N) in/out ----------
__global__ __launch_bounds__(256) void k_win(const float* __restrict__ x,
                                             const float* __restrict__ iw,
                                             const float* __restrict__ ib,
                                             const float* __restrict__ bng,
                                             const float* __restrict__ bnb,
                                             const float* __restrict__ bnm,
                                             const float* __restrict__ bnv,
                                             float* __restrict__ wout){
  __shared__ __align__(16) bf16 xs[64][72];
  __shared__ __align__(16) bf16 wtt[32][72];
  __shared__ __align__(16) bf16 qs[64][72];    // cols 0..15 q, 16..31 zero
  __shared__ __align__(16) bf16 vst[16][72];   // v transposed [ch][token]
  __shared__ __align__(16) bf16 psw[64][72];
  __shared__ float bnsc[32], bnsh[32];
  int s = blockIdx.x >> 7;
  int r7 = blockIdx.x & 127;
  int b = r7 >> 6, wi = r7 & 63;
  int tid = threadIdx.x;
  int wid = tid >> 6, lane = tid & 63;
  int q16 = lane >> 4, l16 = lane & 15;
  for (int f = tid; f < 64 * 48; f += 256){
    int t = f & 63, c = f >> 6;
    int p = (s == 0) ? (((wi >> 3) * 8 + (t >> 3)) * 64 + (wi & 7) * 8 + (t & 7))
          : (s == 1) ? (t * 64 + wi) : (wi * 64 + t);
    xs[t][c] = (bf16)x[((size_t)(b * 48 + c)) * Nn + p];
  }
  for (int f = tid; f < 64 * 16; f += 256){
    int t = f >> 4, j = f & 15;
    xs[t][48 + j] = (bf16)0.f;
    qs[t][16 + j] = (bf16)0.f;
  }
  for (int f = tid; f < 32 * 64; f += 256){
    int o = f >> 6, c = f & 63;
    wtt[o][c] = (c < 48) ? (bf16)iw[(s * 32 + o) * 48 + c] : (bf16)0.f;
  }
  if (tid < 32){
    int ch = s * 32 + tid;
    float sc = bng[ch] * rsqrtf(bnv[ch] + 1e-5f);
    bnsc[tid] = sc;
    bnsh[tid] = (ib[ch] - bnm[ch]) * sc + bnb[ch];
  }
  __syncthreads();
  {
    bf16x8 a0 = *(const bf16x8*)&xs[wid * 16 + l16][q16 * 8];
    bf16x8 a1 = *(const bf16x8*)&xs[wid * 16 + l16][32 + q16 * 8];
    #pragma unroll
    for (int nt = 0; nt < 2; nt++){
      bf16x8 b0 = *(const bf16x8*)&wtt[nt * 16 + l16][q16 * 8];
      bf16x8 b1 = *(const bf16x8*)&wtt[nt * 16 + l16][32 + q16 * 8];
      f32x4 acc = (f32x4){0.f, 0.f, 0.f, 0.f};
      acc = __builtin_amdgcn_mfma_f32_16x16x32_bf16(a0, b0, acc, 0, 0, 0);
      acc = __builtin_amdgcn_mfma_f32_16x16x32_bf16(a1, b1, acc, 0, 0, 0);
      float scv = bnsc[nt * 16 + l16], shv = bnsh[nt * 16 + l16];
      #pragma unroll
      for (int r = 0; r < 4; r++){
        float v = fmaf(acc[r], scv, shv);
        int tok = wid * 16 + q16 * 4 + r;
        if (nt == 0) qs[tok][l16] = (bf16)v;       // C-layout: col=channel
        else         vst[l16][tok] = (bf16)v;      // transposed
      }
    }
  }
  __syncthreads();
  f32x4 sreg[4];
  {
    bf16x8 aq = *(const bf16x8*)&qs[wid * 16 + l16][q16 * 8];
    #pragma unroll
    for (int nt = 0; nt < 4; nt++){
      bf16x8 bq = *(const bf16x8*)&qs[nt * 16 + l16][q16 * 8];
      f32x4 acc = (f32x4){0.f, 0.f, 0.f, 0.f};
      sreg[nt] = __builtin_amdgcn_mfma_f32_16x16x32_bf16(aq, bq, acc, 0, 0, 0);
    }
  }
  float rinv[4];
  #pragma unroll
  for (int r = 0; r < 4; r++){
    float mx = fmaxf(fmaxf(sreg[0][r], sreg[1][r]), fmaxf(sreg[2][r], sreg[3][r]));
    #pragma unroll
    for (int msk = 1; msk < 16; msk <<= 1) mx = fmaxf(mx, __shfl_xor(mx, msk));
    float sum = 0.f;
    #pragma unroll
    for (int nt = 0; nt < 4; nt++){
      float e = __expf(sreg[nt][r] - mx);
      sum += e;
      psw[wid * 16 + q16 * 4 + r][nt * 16 + l16] = (bf16)e;
    }
    #pragma unroll
    for (int msk = 1; msk < 16; msk <<= 1) sum += __shfl_xor(sum, msk);
    rinv[r] = 1.f / sum;
  }
  f32x4 oac = (f32x4){0.f, 0.f, 0.f, 0.f};
  {
    bf16x8 pa0 = *(const bf16x8*)&psw[wid * 16 + l16][q16 * 8];
    bf16x8 pa1 = *(const bf16x8*)&psw[wid * 16 + l16][32 + q16 * 8];
    bf16x8 vb0 = *(const bf16x8*)&vst[l16][q16 * 8];
    bf16x8 vb1 = *(const bf16x8*)&vst[l16][32 + q16 * 8];
    oac = __builtin_amdgcn_mfma_f32_16x16x32_bf16(pa0, vb0, oac, 0, 0, 0);
    oac = __builtin_amdgcn_mfma_f32_16x16x32_bf16(pa1, vb1, oac, 0, 0, 0);
  }
  #pragma unroll
  for (int r = 0; r < 4; r++){
    int tok = wid * 16 + q16 * 4 + r;
    int p = (s == 0) ? (((wi >> 3) * 8 + (tok >> 3)) * 64 + (wi & 7) * 8 + (tok & 7))
          : (s == 1) ? (tok * 64 + wi) : (wi * 64 + tok);
    wout[((size_t)(b * 48 + s * 16 + l16)) * Nn + p] = oac[r] * rinv[r];
  }
}

// ---------------- K6: pout conv + split-K merge + 0.5/0.5 mix (R10) ----------
__global__ void k_final(const float* __restrict__ win, const float* __restrict__ pw,
                        const float* __restrict__ pb, const float* __restrict__ o_part,
                        const float* __restrict__ s_part, float* __restrict__ out){
  int chunk = blockIdx.x & 15;
  int o = (blockIdx.x >> 4) % Cch;
  int b = blockIdx.x / (16 * Cch);
  int p = chunk * 256 + threadIdx.x;
  float acc = pb[o];
  const float* ip = win + (b * Cch) * Nn + p;
  const float* wp = pw + o * Cch;
  #pragma unroll
  for (int c = 0; c < Cch; c++) acc += wp[c] * ip[c * Nn];
  float sden = s_part[(size_t)(b * 2) * Nn + p] + s_part[(size_t)(b * 2 + 1) * Nn + p];
  float odv = (o_part[((size_t)(b * 2) * Cch + o) * Nn + p]
             + o_part[((size_t)(b * 2 + 1) * Cch + o) * Nn + p]) / sden;
  out[(b * Cch + o) * Nn + p] = 0.5f * acc + 0.5f * odv;
}

extern "C" void kernel_launch(void* const* d_in, const int* in_sizes, int n_in,
                              void* d_out, int out_size, void* d_ws, size_t ws_size,
                              hipStream_t stream){
  const float* x   = (const float*)d_in[0];
  const float* Wq  = (const float*)d_in[1];
  const float* bq  = (const float*)d_in[2];
  const float* dww = (const float*)d_in[3];
  const float* dwb = (const float*)d_in[4];
  const float* lng = (const float*)d_in[5];
  const float* lnb = (const float*)d_in[6];
  const float* pww = (const float*)d_in[7];
  const float* Wk  = (const float*)d_in[8];
  const float* bk  = (const float*)d_in[9];
  const float* Wv  = (const float*)d_in[10];
  const float* bv  = (const float*)d_in[11];
  const float* iw  = (const float*)d_in[12];
  const float* ib  = (const float*)d_in[13];
  const float* bng = (const float*)d_in[14];
  const float* bnb = (const float*)d_in[15];
  const float* bnm = (const float*)d_in[16];
  const float* bnv = (const float*)d_in[17];
  const float* pw  = (const float*)d_in[18];
  const float* pb  = (const float*)d_in[19];
  const float* rpe = (const float*)d_in[20];

  // Workspace (f32-slot offsets). qnc aliases o_part[0,393216): qnc dead after
  // k_offset_pos, o_part written later by k_attn.
  float*  ws     = (float*)d_ws;
  float*  qnc    = ws;                    // [0,       393216)  dead after K2
  float*  o_part = ws;                    // [0,       786432)
  float*  pos    = ws + 786432;           // [786432,  802816)
  float2* axay   = (float2*)(ws + 802816);// 8192 float2 -> [802816, 819200)
  float*  wout   = ws + 819200;           // (B,C,N)     [819200, 1212416)
  bf16*   q_bf   = (bf16*)(ws + 1212416); // 524288 bf16 -> [1212416,1474560)
  bf16*   kk_bf  = (bf16*)(ws + 1474560); // 524288 bf16 -> [1474560,1736704)
  bf16*   vt_bf  = (bf16*)(ws + 1736704); // 393216 bf16 -> [1736704,1933312)
  float*  s_part = ws + 1933312;          // [1933312,1949696) = 7.8 MB total
  float*  out    = (float*)d_out;

  k_conv1x1   <<<Bsz * Cch * 16, 256, 0, stream>>>(x, Wq, bq, qnc, q_bf);
  k_offset_pos<<<(Bsz * Nn) / 4, 256, 0, stream>>>(qnc, dww, dwb, lng, lnb, pww, pos);
  k_samplekv  <<<(Bsz * Nn) / 8, 512, 0, stream>>>(x, pos, Wk, bk, Wv, bv,
                                                   kk_bf, vt_bf, axay);
  k_attn      <<<Bsz * 512, 256, 0, stream>>>(q_bf, kk_bf, vt_bf, axay, rpe,
                                              o_part, s_part);
  k_win       <<<384, 256, 0, stream>>>(x, iw, ib, bng, bnb, bnm, bnv, wout);
  k_final     <<<Bsz * Cch * 16, 256, 0, stream>>>(wout, pw, pb, o_part,
                                                   s_part, out);
}

// Round 13
// 199.609 us; speedup vs baseline: 1.2335x; 1.0339x over previous
//
#include <hip/hip_runtime.h>
#include <hip/hip_bf16.h>
#include <math.h>

#define Bsz 2
#define Cch 48
#define Hh 64
#define Ww 64
#define Nn 4096

typedef __bf16 bf16;
typedef __attribute__((ext_vector_type(8))) __bf16 bf16x8;
typedef __attribute__((ext_vector_type(4))) float f32x4;

// ---------------- K1: conv1x1 -> qnc (B,N,48) fp32 + q_bf (B,N,64) bf16 -----
__global__ void k_conv1x1(const float* __restrict__ in, const float* __restrict__ Wt,
                          const float* __restrict__ bias, float* __restrict__ qnc,
                          bf16* __restrict__ qbf){
  int chunk = blockIdx.x & 15;            // N/256 = 16 chunks
  int o = (blockIdx.x >> 4) % Cch;
  int b = blockIdx.x / (16 * Cch);
  int p = chunk * 256 + threadIdx.x;
  float acc = bias[o];
  const float* ip = in + (b * Cch) * Nn + p;
  const float* wp = Wt + o * Cch;
  #pragma unroll
  for (int c = 0; c < Cch; c++) acc += wp[c] * ip[c * Nn];
  qnc[((size_t)(b * Nn + p)) * 48 + o] = acc;
  size_t qb = ((size_t)(b * Nn + p)) * 64;
  qbf[qb + o] = (bf16)acc;
  if (o < 16) qbf[qb + 48 + o] = (bf16)0.f;   // zero-pad k=48..63
}

// ---------------- K2: wave-per-pixel dw3x3 + LN + GELU + pw + tanh -> pos ----
__global__ __launch_bounds__(256) void k_offset_pos(const float* __restrict__ qnc,
                             const float* __restrict__ dww,
                             const float* __restrict__ dwb, const float* __restrict__ lng,
                             const float* __restrict__ lnb, const float* __restrict__ pww,
                             float* __restrict__ pos){
  int wv = threadIdx.x >> 6, lane = threadIdx.x & 63;
  int idx = blockIdx.x * 4 + wv;          // (b,pixel)
  int b = idx >> 12;
  int p = idx & (Nn - 1);
  int y = p >> 6, x = p & 63;
  int c = lane;
  float t = 0.f;
  if (c < 48){
    t = dwb[c];
    #pragma unroll
    for (int ky = -1; ky <= 1; ky++){
      int yy = y + ky;
      if (yy < 0 || yy >= Hh) continue;          // wave-uniform branch
      #pragma unroll
      for (int kx = -1; kx <= 1; kx++){
        int xx = x + kx;
        if (xx < 0 || xx >= Ww) continue;        // wave-uniform branch
        t = fmaf(qnc[((size_t)(b * Nn + yy * Ww + xx)) * 48 + c],
                 dww[c * 9 + (ky + 1) * 3 + (kx + 1)], t);
      }
    }
  }
  float s = t;
  #pragma unroll
  for (int m = 1; m < 64; m <<= 1) s += __shfl_xor(s, m);
  float mean = s * (1.f / 48.f);
  float d = (c < 48) ? (t - mean) : 0.f;
  float v = d * d;
  #pragma unroll
  for (int m = 1; m < 64; m <<= 1) v += __shfl_xor(v, m);
  float rstd = rsqrtf(v * (1.f / 48.f) + 1e-5f);
  float p0 = 0.f, p1 = 0.f;
  if (c < 48){
    float u = (t - mean) * rstd * lng[c] + lnb[c];
    u = 0.5f * u * (1.f + erff(u * 0.70710678118654752f));   // exact gelu
    p0 = pww[c] * u;
    p1 = pww[48 + c] * u;
  }
  #pragma unroll
  for (int m = 1; m < 64; m <<= 1){ p0 += __shfl_xor(p0, m); p1 += __shfl_xor(p1, m); }
  if (lane == 0){
    float posy = tanhf(p0) * (2.f / 63.f) + ((0.5f + (float)y) * (2.f / 63.f) - 1.f);
    float posx = tanhf(p1) * (2.f / 63.f) + ((0.5f + (float)x) * (2.f / 63.f) - 1.f);
    pos[idx * 2 + 0] = posy;
    pos[idx * 2 + 1] = posx;
  }
}

// ---------------- K3: wave-per-key fused sample + k,v projection -------------
__global__ __launch_bounds__(512) void k_samplekv(const float* __restrict__ x,
                           const float* __restrict__ pos,
                           const float* __restrict__ Wk, const float* __restrict__ bk,
                           const float* __restrict__ Wv, const float* __restrict__ bv,
                           bf16* __restrict__ kk_bf, bf16* __restrict__ vt_bf,
                           float2* __restrict__ axay){
  __shared__ float wkt[48][49];   // wkt[c][o] = Wk[o][c]
  __shared__ float wvt[48][49];
  __shared__ float rowb[8][48];
  int tid = threadIdx.x;
  for (int f = tid; f < 2304; f += 512){
    int o = f / 48, c = f - o * 48;
    wkt[c][o] = Wk[f];
    wvt[c][o] = Wv[f];
  }
  __syncthreads();
  int wv = tid >> 6, lane = tid & 63;
  int idx = blockIdx.x * 8 + wv;
  int b = idx >> 12;
  int n = idx & (Nn - 1);
  float py = pos[idx * 2], px = pos[idx * 2 + 1];
  if (lane == 0) axay[idx] = make_float2(95.f - 47.5f * py, 95.f - 47.5f * px);
  float gx = (px + 1.f) * 0.5f * 63.f;
  float gy = (py + 1.f) * 0.5f * 63.f;
  float x0f = floorf(gx), y0f = floorf(gy);
  float wx = gx - x0f, wy = gy - y0f;
  int x0 = (int)x0f, y0 = (int)y0f, x1 = x0 + 1, y1 = y0 + 1;
  float w00 = (1.f - wy) * (1.f - wx), w01 = (1.f - wy) * wx;
  float w10 = wy * (1.f - wx),         w11 = wy * wx;
  bool vx0 = (x0 >= 0) && (x0 < Ww), vx1 = (x1 >= 0) && (x1 < Ww);
  bool vy0 = (y0 >= 0) && (y0 < Hh), vy1 = (y1 >= 0) && (y1 < Hh);
  if (!(vx0 && vy0)) w00 = 0.f;
  if (!(vx1 && vy0)) w01 = 0.f;
  if (!(vx0 && vy1)) w10 = 0.f;
  if (!(vx1 && vy1)) w11 = 0.f;
  int cx0 = min(max(x0, 0), Ww - 1), cx1 = min(max(x1, 0), Ww - 1);
  int cy0 = min(max(y0, 0), Hh - 1), cy1 = min(max(y1, 0), Hh - 1);
  int i00 = cy0 * Ww + cx0, i01 = cy0 * Ww + cx1;
  int i10 = cy1 * Ww + cx0, i11 = cy1 * Ww + cx1;
  int c = lane;
  if (c < 48){
    const float* xc = x + ((size_t)(b * Cch + c)) * Nn;
    rowb[wv][c] = w00 * xc[i00] + w01 * xc[i01] + w10 * xc[i10] + w11 * xc[i11];
  }
  // same-wave LDS RAW: compiler inserts lgkmcnt; no barrier needed
  int o = lane;
  if (o < 48){
    float ka = bk[o], va = bv[o];
    #pragma unroll
    for (int cc = 0; cc < 48; cc++){
      float r = rowb[wv][cc];                 // broadcast
      ka = fmaf(wkt[cc][o], r, ka);           // conflict-free (pad 49)
      va = fmaf(wvt[cc][o], r, va);
    }
    kk_bf[(size_t)idx * 64 + o] = (bf16)ka;                  // coalesced
    vt_bf[((size_t)(b * Cch + o)) * Nn + n] = (bf16)va;      // 48-CL scatter, 1 instr
  }
  if (o < 16) kk_bf[(size_t)idx * 64 + 48 + o] = (bf16)0.f;  // zero-pad
}

// ---------------- K4: FUSED attention (blocks 0..1023) + window attn (1024+) -
// attn path: R12 barrier-free loop + (a) zeros-in-g branchless bias
// (j0 = x0-xlo in [0,24] by monotonicity: 1.508*15=22.6 -> floor-diff <= 23),
// (b) denominator shuffle-reduce moved to epilogue.
// win path: R12 k_win with psw overlaid on xs. LDS union 25.6KB -> 5 blk/CU.
__global__ __launch_bounds__(256, 5) void k_attn_win(const bf16* __restrict__ q_bf,
                                              const bf16* __restrict__ kk_bf,
                                              const bf16* __restrict__ vt_bf,
                                              const float2* __restrict__ axay,
                                              const float* __restrict__ rpe,
                                              float* __restrict__ o_part,
                                              float* __restrict__ s_part,
                                              const float* __restrict__ x,
                                              const float* __restrict__ iw,
                                              const float* __restrict__ ib,
                                              const float* __restrict__ bng,
                                              const float* __restrict__ bnb,
                                              const float* __restrict__ bnm,
                                              const float* __restrict__ bnv,
                                              float* __restrict__ wout){
  __shared__ __align__(16) char smem[25600];
  const int tid = threadIdx.x;
  const int wid = tid >> 6, lane = tid & 63;
  const int q16 = lane >> 4, l16 = lane & 15;

  if (blockIdx.x < 1024){
    // ================= deformable attention path =================
    float (*g)[26] = (float(*)[26])smem;                 // 13312
    float* axs  = (float*)(smem + 13312);                // 512
    int*   xlos = (int*)  (smem + 13824);                // 512
    float* wy0s = (float*)(smem + 14336);                // 512
    float* wy1s = (float*)(smem + 14848);                // 512
    int*   r0s  = (int*)  (smem + 15360);                // 512
    int*   r1s  = (int*)  (smem + 15872);                // 512
    bf16 (*ps)[136] = (bf16(*)[136])(smem + 16384);      // 4352 -> 20736

    const int b  = blockIdx.x >> 9;
    const int kp = (blockIdx.x >> 8) & 1;
    const int m0 = (blockIdx.x & 255) * 16;
    const int wn0 = wid * 32;

    const bf16* qb = q_bf + ((size_t)(b * Nn + m0 + l16)) * 64;
    bf16x8 qf0 = *(const bf16x8*)(qb + q16 * 8);
    bf16x8 qf1 = *(const bf16x8*)(qb + 32 + q16 * 8);

    const float qgy = (float)(m0 >> 6) * (2.f / 63.f) - 1.f;
    const float byq = 47.5f * qgy;              // gyr = ay + byq
    const float scale = 0.14433756729740643f;   // 48^-0.5
    const float bx0 = 47.5f * ((float)(m0 & 63) * (2.f / 63.f) - 1.f);
    float bxr[4];
    #pragma unroll
    for (int r = 0; r < 4; r++){
      int mcol = (m0 & 63) + q16 * 4 + r;
      bxr[r] = 47.5f * ((float)mcol * (2.f / 63.f) - 1.f);
    }

    f32x4 oacc[3];
    #pragma unroll
    for (int ct = 0; ct < 3; ct++) oacc[ct] = (f32x4){0.f, 0.f, 0.f, 0.f};
    float s_runw[4] = {0.f, 0.f, 0.f, 0.f};   // per-THREAD partials (reduce at end)

    for (int chk = 0; chk < 16; chk++){
      const int n0 = kp * 2048 + chk * 128;
      // per-wave bilinear params: lane<32 handles key wn0+lane
      if (lane < 32){
        int n = wn0 + lane;
        float2 aa = axay[(size_t)b * Nn + n0 + n];  // (ay, ax)
        float gyr = aa.x + byq;
        float y0f = floorf(gyr);
        float wy = gyr - y0f;
        int y0 = (int)y0f, y1 = y0 + 1;
        wy0s[n] = ((unsigned)y0 < 191u) ? (1.f - wy) : 0.f;
        wy1s[n] = ((unsigned)y1 < 191u) ? wy : 0.f;
        r0s[n] = min(max(y0, 0), 190) * 191;
        r1s[n] = min(max(y1, 0), 190) * 191;
        axs[n] = aa.y;
        xlos[n] = (int)floorf(aa.y + bx0);
      }
      // g-build: wave's own 32 keys; zero value outside x-range (branchless bias)
      {
        int s = lane >> 5, jj = lane & 31;
        if (jj < 26){
          #pragma unroll
          for (int it = 0; it < 16; it++){
            int n = wn0 + it * 2 + s;
            int xg = xlos[n] + jj;
            int cx = min(max(xg, 0), 190);
            float val = wy0s[n] * rpe[r0s[n] + cx] + wy1s[n] * rpe[r1s[n] + cx];
            g[n][jj] = ((unsigned)xg < 191u) ? val : 0.f;
          }
        }
      }
      // QK^T MFMA: B-fragments direct from global (L2-hot)
      f32x4 s0 = (f32x4){0.f, 0.f, 0.f, 0.f};
      f32x4 s1 = (f32x4){0.f, 0.f, 0.f, 0.f};
      {
        const bf16* kg = kk_bf + (size_t)(b * Nn + n0 + wn0 + l16) * 64;
        bf16x8 b00 = *(const bf16x8*)(kg + q16 * 8);
        bf16x8 b01 = *(const bf16x8*)(kg + 32 + q16 * 8);
        bf16x8 b10 = *(const bf16x8*)(kg + 16 * 64 + q16 * 8);
        bf16x8 b11 = *(const bf16x8*)(kg + 16 * 64 + 32 + q16 * 8);
        s0 = __builtin_amdgcn_mfma_f32_16x16x32_bf16(qf0, b00, s0, 0, 0, 0);
        s0 = __builtin_amdgcn_mfma_f32_16x16x32_bf16(qf1, b01, s0, 0, 0, 0);
        s1 = __builtin_amdgcn_mfma_f32_16x16x32_bf16(qf0, b10, s1, 0, 0, 0);
        s1 = __builtin_amdgcn_mfma_f32_16x16x32_bf16(qf1, b11, s1, 0, 0, 0);
      }
      // branchless bias + exp (no max-sub; logits bounded)
      #pragma unroll
      for (int nt = 0; nt < 2; nt++){
        int nl = wn0 + nt * 16 + l16;
        float ax = axs[nl];
        int xb = xlos[nl];
        f32x4 sv = nt ? s1 : s0;
        #pragma unroll
        for (int r = 0; r < 4; r++){
          float gxr = ax + bxr[r];
          float x0f = floorf(gxr);
          float wx = gxr - x0f;
          int j0 = (int)x0f - xb;              // in [0,24] (proved)
          float g0 = g[nl][j0], g1 = g[nl][j0 + 1];
          float bias = fmaf(wx, g1 - g0, g0);
          float e = __expf(fmaf(sv[r], scale, bias));
          s_runw[r] += e;
          ps[q16 * 4 + r][nl] = (bf16)e;
        }
      }
      // PV MFMA: A=ps (same-wave), B=V direct from global
      {
        bf16x8 pa = *(const bf16x8*)&ps[l16][wn0 + q16 * 8];
        const bf16* vgb = vt_bf + (size_t)(b * Cch + l16) * Nn + n0 + wn0 + q16 * 8;
        #pragma unroll
        for (int ct = 0; ct < 3; ct++){
          bf16x8 vb = *(const bf16x8*)(vgb + (size_t)(ct * 16) * Nn);
          oacc[ct] = __builtin_amdgcn_mfma_f32_16x16x32_bf16(pa, vb, oacc[ct], 0, 0, 0);
        }
      }
    }
    // deferred denominator reduce (once, not per chunk)
    #pragma unroll
    for (int r = 0; r < 4; r++){
      #pragma unroll
      for (int msk = 1; msk < 16; msk <<= 1)
        s_runw[r] += __shfl_xor(s_runw[r], msk);
    }
    // epilogue: cross-wave plain sums (scratch aliases g/axs)
    __syncthreads();
    float* ored = (float*)g;         // 64x48 f32 = 12288 <= 13312
    float* sred = axs;               // 64 floats
    #pragma unroll
    for (int ct = 0; ct < 3; ct++)
      #pragma unroll
      for (int r = 0; r < 4; r++)
        ored[(wid * 16 + q16 * 4 + r) * 48 + ct * 16 + l16] = oacc[ct][r];
    if (l16 == 0){
      #pragma unroll
      for (int r = 0; r < 4; r++) sred[wid * 16 + q16 * 4 + r] = s_runw[r];
    }
    __syncthreads();
    size_t obase = ((size_t)(b * 2 + kp) * Cch) * Nn;
    #pragma unroll
    for (int e = 0; e < 3; e++){
      int idx = tid + e * 256;         // 768 = 48c x 16m
      int c = idx >> 4, mm = idx & 15;
      float v = ored[mm * 48 + c] + ored[(16 + mm) * 48 + c]
              + ored[(32 + mm) * 48 + c] + ored[(48 + mm) * 48 + c];
      o_part[obase + (size_t)c * Nn + m0 + mm] = v;
    }
    if (tid < 16)
      s_part[(size_t)(b * 2 + kp) * Nn + m0 + tid] =
          sred[tid] + sred[16 + tid] + sred[32 + tid] + sred[48 + tid];
  } else {
    // ================= window attention path =================
    bf16 (*xs)[72]  = (bf16(*)[72])smem;                  // 9216 (later psw)
    bf16 (*wtt)[72] = (bf16(*)[72])(smem + 9216);         // 4608
    bf16 (*qs)[72]  = (bf16(*)[72])(smem + 13824);        // 9216
    bf16 (*vst)[72] = (bf16(*)[72])(smem + 23040);        // 2304
    float* bnsc = (float*)(smem + 25344);                 // 128
    float* bnsh = (float*)(smem + 25472);                 // 128 -> 25600
    bf16 (*psw)[72] = xs;   // overlay: xs dead after proj barrier

    int wb = blockIdx.x - 1024;
    int s = wb >> 7;
    int r7 = wb & 127;
    int b = r7 >> 6, wi = r7 & 63;
    for (int f = tid; f < 64 * 48; f += 256){
      int t = f & 63, c = f >> 6;
      int p = (s == 0) ? (((wi >> 3) * 8 + (t >> 3)) * 64 + (wi & 7) * 8 + (t & 7))
            : (s == 1) ? (t * 64 + wi) : (wi * 64 + t);
      xs[t][c] = (bf16)x[((size_t)(b * 48 + c)) * Nn + p];
    }
    for (int f = tid; f < 64 * 16; f += 256){
      int t = f >> 4, j = f & 15;
      xs[t][48 + j] = (bf16)0.f;
      qs[t][16 + j] = (bf16)0.f;
    }
    for (int f = tid; f < 32 * 64; f += 256){
      int o = f >> 6, c = f & 63;
      wtt[o][c] = (c < 48) ? (bf16)iw[(s * 32 + o) * 48 + c] : (bf16)0.f;
    }
    if (tid < 32){
      int ch = s * 32 + tid;
      float sc = bng[ch] * rsqrtf(bnv[ch] + 1e-5f);
      bnsc[tid] = sc;
      bnsh[tid] = (ib[ch] - bnm[ch]) * sc + bnb[ch];
    }
    __syncthreads();
    {
      bf16x8 a0 = *(const bf16x8*)&xs[wid * 16 + l16][q16 * 8];
      bf16x8 a1 = *(const bf16x8*)&xs[wid * 16 + l16][32 + q16 * 8];
      #pragma unroll
      for (int nt = 0; nt < 2; nt++){
        bf16x8 b0 = *(const bf16x8*)&wtt[nt * 16 + l16][q16 * 8];
        bf16x8 b1 = *(const bf16x8*)&wtt[nt * 16 + l16][32 + q16 * 8];
        f32x4 acc = (f32x4){0.f, 0.f, 0.f, 0.f};
        acc = __builtin_amdgcn_mfma_f32_16x16x32_bf16(a0, b0, acc, 0, 0, 0);
        acc = __builtin_amdgcn_mfma_f32_16x16x32_bf16(a1, b1, acc, 0, 0, 0);
        float scv = bnsc[nt * 16 + l16], shv = bnsh[nt * 16 + l16];
        #pragma unroll
        for (int r = 0; r < 4; r++){
          float v = fmaf(acc[r], scv, shv);
          int tok = wid * 16 + q16 * 4 + r;
          if (nt == 0) qs[tok][l16] = (bf16)v;       // C-layout: col=channel
          else         vst[l16][tok] = (bf16)v;      // transposed
        }
      }
    }
    __syncthreads();   // all waves done with xs -> safe to overlay psw
    f32x4 sreg[4];
    {
      bf16x8 aq = *(const bf16x8*)&qs[wid * 16 + l16][q16 * 8];
      #pragma unroll
      for (int nt = 0; nt < 4; nt++){
        bf16x8 bq = *(const bf16x8*)&qs[nt * 16 + l16][q16 * 8];
        f32x4 acc = (f32x4){0.f, 0.f, 0.f, 0.f};
        sreg[nt] = __builtin_amdgcn_mfma_f32_16x16x32_bf16(aq, bq, acc, 0, 0, 0);
      }
    }
    float rinv[4];
    #pragma unroll
    for (int r = 0; r < 4; r++){
      float mx = fmaxf(fmaxf(sreg[0][r], sreg[1][r]), fmaxf(sreg[2][r], sreg[3][r]));
      #pragma unroll
      for (int msk = 1; msk < 16; msk <<= 1) mx = fmaxf(mx, __shfl_xor(mx, msk));
      float sum = 0.f;
      #pragma unroll
      for (int nt = 0; nt < 4; nt++){
        float e = __expf(sreg[nt][r] - mx);
        sum += e;
        psw[wid * 16 + q16 * 4 + r][nt * 16 + l16] = (bf16)e;
      }
      #pragma unroll
      for (int msk = 1; msk < 16; msk <<= 1) sum += __shfl_xor(sum, msk);
      rinv[r] = 1.f / sum;
    }
    f32x4 oac = (f32x4){0.f, 0.f, 0.f, 0.f};
    {
      bf16x8 pa0 = *(const bf16x8*)&psw[wid * 16 + l16][q16 * 8];
      bf16x8 pa1 = *(const bf16x8*)&psw[wid * 16 + l16][32 + q16 * 8];
      bf16x8 vb0 = *(const bf16x8*)&vst[l16][q16 * 8];
      bf16x8 vb1 = *(const bf16x8*)&vst[l16][32 + q16 * 8];
      oac = __builtin_amdgcn_mfma_f32_16x16x32_bf16(pa0, vb0, oac, 0, 0, 0);
      oac = __builtin_amdgcn_mfma_f32_16x16x32_bf16(pa1, vb1, oac, 0, 0, 0);
    }
    #pragma unroll
    for (int r = 0; r < 4; r++){
      int tok = wid * 16 + q16 * 4 + r;
      int p = (s == 0) ? (((wi >> 3) * 8 + (tok >> 3)) * 64 + (wi & 7) * 8 + (tok & 7))
            : (s == 1) ? (tok * 64 + wi) : (wi * 64 + tok);
      wout[((size_t)(b * 48 + s * 16 + l16)) * Nn + p] = oac[r] * rinv[r];
    }
  }
}

// ---------------- K5: pout conv + split-K merge + 0.5/0.5 mix ----------------
__global__ void k_final(const float* __restrict__ win, const float* __restrict__ pw,
                        const float* __restrict__ pb, const float* __restrict__ o_part,
                        const float* __restrict__ s_part, float* __restrict__ out){
  int chunk = blockIdx.x & 15;
  int o = (blockIdx.x >> 4) % Cch;
  int b = blockIdx.x / (16 * Cch);
  int p = chunk * 256 + threadIdx.x;
  float acc = pb[o];
  const float* ip = win + (b * Cch) * Nn + p;
  const float* wp = pw + o * Cch;
  #pragma unroll
  for (int c = 0; c < Cch; c++) acc += wp[c] * ip[c * Nn];
  float sden = s_part[(size_t)(b * 2) * Nn + p] + s_part[(size_t)(b * 2 + 1) * Nn + p];
  float odv = (o_part[((size_t)(b * 2) * Cch + o) * Nn + p]
             + o_part[((size_t)(b * 2 + 1) * Cch + o) * Nn + p]) / sden;
  out[(b * Cch + o) * Nn + p] = 0.5f * acc + 0.5f * odv;
}

extern "C" void kernel_launch(void* const* d_in, const int* in_sizes, int n_in,
                              void* d_out, int out_size, void* d_ws, size_t ws_size,
                              hipStream_t stream){
  const float* x   = (const float*)d_in[0];
  const float* Wq  = (const float*)d_in[1];
  const float* bq  = (const float*)d_in[2];
  const float* dww = (const float*)d_in[3];
  const float* dwb = (const float*)d_in[4];
  const float* lng = (const float*)d_in[5];
  const float* lnb = (const float*)d_in[6];
  const float* pww = (const float*)d_in[7];
  const float* Wk  = (const float*)d_in[8];
  const float* bk  = (const float*)d_in[9];
  const float* Wv  = (const float*)d_in[10];
  const float* bv  = (const float*)d_in[11];
  const float* iw  = (const float*)d_in[12];
  const float* ib  = (const float*)d_in[13];
  const float* bng = (const float*)d_in[14];
  const float* bnb = (const float*)d_in[15];
  const float* bnm = (const float*)d_in[16];
  const float* bnv = (const float*)d_in[17];
  const float* pw  = (const float*)d_in[18];
  const float* pb  = (const float*)d_in[19];
  const float* rpe = (const float*)d_in[20];

  // Workspace (f32-slot offsets). qnc aliases o_part[0,393216): qnc dead after
  // k_offset_pos, o_part written later by k_attn_win.
  float*  ws     = (float*)d_ws;
  float*  qnc    = ws;                    // [0,       393216)  dead after K2
  float*  o_part = ws;                    // [0,       786432)
  float*  pos    = ws + 786432;           // [786432,  802816)
  float2* axay   = (float2*)(ws + 802816);// 8192 float2 -> [802816, 819200)
  float*  wout   = ws + 819200;           // (B,C,N)     [819200, 1212416)
  bf16*   q_bf   = (bf16*)(ws + 1212416); // 524288 bf16 -> [1212416,1474560)
  bf16*   kk_bf  = (bf16*)(ws + 1474560); // 524288 bf16 -> [1474560,1736704)
  bf16*   vt_bf  = (bf16*)(ws + 1736704); // 393216 bf16 -> [1736704,1933312)
  float*  s_part = ws + 1933312;          // [1933312,1949696) = 7.8 MB total
  float*  out    = (float*)d_out;

  k_conv1x1   <<<Bsz * Cch * 16, 256, 0, stream>>>(x, Wq, bq, qnc, q_bf);
  k_offset_pos<<<(Bsz * Nn) / 4, 256, 0, stream>>>(qnc, dww, dwb, lng, lnb, pww, pos);
  k_samplekv  <<<(Bsz * Nn) / 8, 512, 0, stream>>>(x, pos, Wk, bk, Wv, bv,
                                                   kk_bf, vt_bf, axay);
  k_attn_win  <<<Bsz * 512 + 384, 256, 0, stream>>>(q_bf, kk_bf, vt_bf, axay, rpe,
                                                    o_part, s_part,
                                                    x, iw, ib, bng, bnb, bnm, bnv, wout);
  k_final     <<<Bsz * Cch * 16, 256, 0, stream>>>(wout, pw, pb, o_part,
                                                   s_part, out);
}